// Round 1
// baseline (485.193 us; speedup 1.0000x reference)
//
#include <hip/hip_runtime.h>

// RobustSum: M = A@V; 3x { dist=cdist(M,V); w=1/(dist+eps); ww=w*A;
//                          M = (ww/rowsum(ww)) @ V }   (T=1.0)
// All GEMMs in bf16 MFMA (fp32 accumulate); tolerance is 2% of ref absmax.

typedef __bf16 bf16;
typedef bf16 bf16x4 __attribute__((ext_vector_type(4)));
typedef bf16 bf16x8 __attribute__((ext_vector_type(8)));
typedef float f32x4 __attribute__((ext_vector_type(4)));

#define S_DIM 2048
#define D_DIM 512
#define NB    4
#define EPSILON 0.01f

// ---------------- cast fp32 -> bf16 (vectorized x4) ----------------
__global__ void cast_kernel(const float* __restrict__ in, bf16* __restrict__ out, int n4) {
  int i = blockIdx.x * blockDim.x + threadIdx.x;
  if (i >= n4) return;
  float4 v = ((const float4*)in)[i];
  bf16x4 o = { (bf16)v.x, (bf16)v.y, (bf16)v.z, (bf16)v.w };
  ((bf16x4*)out)[i] = o;
}

// ---------------- transpose + cast: V (S x D) -> Vt (D x S) ----------------
__global__ void transpose_cast_kernel(const float* __restrict__ V, bf16* __restrict__ Vt) {
  __shared__ float tile[64][68];   // +4 pad breaks bank conflicts on column reads
  int b  = blockIdx.z;
  int c0 = blockIdx.x * 64;        // col of V (row of Vt)
  int r0 = blockIdx.y * 64;        // row of V
  const float* Vb = V  + (size_t)b * S_DIM * D_DIM;
  bf16*       Vtb = Vt + (size_t)b * S_DIM * D_DIM;
  int tx = threadIdx.x & 15, ty = threadIdx.x >> 4;
#pragma unroll
  for (int i = 0; i < 4; ++i) {
    int r = ty + i * 16;
    float4 v = *(const float4*)(Vb + (size_t)(r0 + r) * D_DIM + (c0 + tx * 4));
    tile[r][tx * 4 + 0] = v.x; tile[r][tx * 4 + 1] = v.y;
    tile[r][tx * 4 + 2] = v.z; tile[r][tx * 4 + 3] = v.w;
  }
  __syncthreads();
#pragma unroll
  for (int i = 0; i < 4; ++i) {
    int c = ty + i * 16;  // col of V == row of Vt
    bf16x4 o = { (bf16)tile[tx * 4 + 0][c], (bf16)tile[tx * 4 + 1][c],
                 (bf16)tile[tx * 4 + 2][c], (bf16)tile[tx * 4 + 3][c] };
    *(bf16x4*)(Vtb + (size_t)(c0 + c) * S_DIM + (r0 + tx * 4)) = o;
  }
}

// ---------------- row L2^2 of a (nrows x 512) bf16 matrix, one wave/row ----------------
__global__ void rownorm_kernel(const bf16* __restrict__ X, float* __restrict__ out) {
  int row  = blockIdx.x * 4 + (threadIdx.x >> 6);
  int lane = threadIdx.x & 63;
  bf16x8 v = *(const bf16x8*)(X + (size_t)row * D_DIM + lane * 8);
  float s = 0.f;
#pragma unroll
  for (int i = 0; i < 8; ++i) { float f = (float)v[i]; s += f * f; }
#pragma unroll
  for (int off = 32; off > 0; off >>= 1) s += __shfl_down(s, off);
  if (lane == 0) out[row] = s;
}

// ---------------- NT GEMM: C[M,N] = Amat(MxK) * Bmat(NxK)^T ----------------
// MODE 0: write bf16 C                       (M0 = Abf * Vt)
// MODE 1: dist/weight epilogue -> Wbf + l1   (P  = Mbf * Vbf^T)
// MODE 2: write bf16 C scaled by 1/l1        (M  = Wbf * Vt, iters 0,1)
// MODE 3: write fp32 C scaled by 1/l1        (final output)
template <int MODE>
__global__ __launch_bounds__(256)
void gemm_kernel(const bf16* __restrict__ Amat, const bf16* __restrict__ Bmat,
                 int M, int N, int K,
                 bf16* __restrict__ Cbf, float* __restrict__ Cf,
                 const float* __restrict__ m2, const float* __restrict__ v2,
                 const bf16* __restrict__ Aw, bf16* __restrict__ Wout,
                 float* __restrict__ l1) {
  const int bz   = blockIdx.z;
  const int row0 = blockIdx.y * 128;
  const int col0 = blockIdx.x * 128;
  const bf16* Ab = Amat + (size_t)bz * M * K;
  const bf16* Bb = Bmat + (size_t)bz * N * K;

  __shared__ bf16 ldsA[128 * 32];  // 8 KB, contiguous (global_load_lds constraint: no pad)
  __shared__ bf16 ldsB[128 * 32];

  const int tid  = threadIdx.x;
  const int wave = tid >> 6;
  const int lane = tid & 63;
  const int wr   = wave >> 1;   // wave row (0..1) -> 64 rows
  const int wc   = wave & 1;    // wave col (0..1) -> 64 cols
  const int q    = lane >> 4;   // quad 0..3
  const int c16  = lane & 15;

  f32x4 acc[4][4] = {};

  for (int k0 = 0; k0 < K; k0 += 32) {
    // stage 128x32 bf16 tiles of A and B: 2 issues/wave each, 16B/lane
#pragma unroll
    for (int i = 0; i < 2; ++i) {
      int eoff = (wave * 2 + i) * 512 + lane * 8;  // element index in tile
      int r = eoff >> 5;
      int c = eoff & 31;
      __builtin_amdgcn_global_load_lds(
          (const __attribute__((address_space(1))) void*)(Ab + (size_t)(row0 + r) * K + (k0 + c)),
          (__attribute__((address_space(3))) void*)(ldsA + (wave * 2 + i) * 512), 16, 0, 0);
      __builtin_amdgcn_global_load_lds(
          (const __attribute__((address_space(1))) void*)(Bb + (size_t)(col0 + r) * K + (k0 + c)),
          (__attribute__((address_space(3))) void*)(ldsB + (wave * 2 + i) * 512), 16, 0, 0);
    }
    __syncthreads();   // compiler emits s_waitcnt vmcnt(0) before s_barrier

    bf16x8 afr[4], bfr[4];
#pragma unroll
    for (int mt = 0; mt < 4; ++mt)
      afr[mt] = *(const bf16x8*)(ldsA + (size_t)(wr * 64 + mt * 16 + c16) * 32 + q * 8);
#pragma unroll
    for (int nt = 0; nt < 4; ++nt)
      bfr[nt] = *(const bf16x8*)(ldsB + (size_t)(wc * 64 + nt * 16 + c16) * 32 + q * 8);
#pragma unroll
    for (int mt = 0; mt < 4; ++mt)
#pragma unroll
      for (int nt = 0; nt < 4; ++nt)
        acc[mt][nt] = __builtin_amdgcn_mfma_f32_16x16x32_bf16(afr[mt], bfr[nt], acc[mt][nt], 0, 0, 0);
    __syncthreads();
  }

  // epilogue: C/D layout col = lane&15, row = (lane>>4)*4 + reg  (m89-verified)
  const int rowBase = row0 + wr * 64 + q * 4;
  const int colBase = col0 + wc * 64 + c16;

  if (MODE == 1) {
    const float* m2b  = m2 + (size_t)bz * M;
    const float* v2b  = v2 + (size_t)bz * N;
    const bf16*  Awb  = Aw + (size_t)bz * M * N;
    bf16*        Wob  = Wout + (size_t)bz * M * N;
    float*       l1b  = l1 + (size_t)bz * M;
#pragma unroll
    for (int mt = 0; mt < 4; ++mt) {
#pragma unroll
      for (int r = 0; r < 4; ++r) {
        int gi = rowBase + mt * 16 + r;
        float m2v = m2b[gi];
        float rs = 0.f;
#pragma unroll
        for (int nt = 0; nt < 4; ++nt) {
          int gj = colBase + nt * 16;
          float p  = acc[mt][nt][r];
          float d2 = fmaxf(m2v + v2b[gj] - 2.f * p, 0.f);
          float w  = 1.f / (sqrtf(d2) + EPSILON);
          float a  = (float)Awb[(size_t)gi * N + gj];
          float ww = w * a;
          Wob[(size_t)gi * N + gj] = (bf16)ww;
          rs += fabsf(ww);
        }
        rs += __shfl_xor(rs, 1);
        rs += __shfl_xor(rs, 2);
        rs += __shfl_xor(rs, 4);
        rs += __shfl_xor(rs, 8);
        if (c16 == 0) atomicAdd(&l1b[gi], rs);
      }
    }
  } else {
#pragma unroll
    for (int mt = 0; mt < 4; ++mt) {
#pragma unroll
      for (int r = 0; r < 4; ++r) {
        int gi = rowBase + mt * 16 + r;
        float sc = 1.f;
        if (MODE >= 2) sc = 1.f / fmaxf((l1 + (size_t)bz * M)[gi], 1e-12f);
#pragma unroll
        for (int nt = 0; nt < 4; ++nt) {
          int gj = colBase + nt * 16;
          float v = acc[mt][nt][r] * sc;
          if (MODE == 3) (Cf + (size_t)bz * M * N)[(size_t)gi * N + gj] = v;
          else           (Cbf + (size_t)bz * M * N)[(size_t)gi * N + gj] = (bf16)v;
        }
      }
    }
  }
}

extern "C" void kernel_launch(void* const* d_in, const int* in_sizes, int n_in,
                              void* d_out, int out_size, void* d_ws, size_t ws_size,
                              hipStream_t stream) {
  const float* A = (const float*)d_in[0];  // (4, 2048, 2048)
  const float* V = (const float*)d_in[1];  // (4, 2048, 512)
  float* out = (float*)d_out;              // (4, 2048, 512) fp32

  char* ws = (char*)d_ws;
  bf16* Abf = (bf16*)ws;  ws += (size_t)NB * S_DIM * S_DIM * 2;   // 33.5 MB
  bf16* Vbf = (bf16*)ws;  ws += (size_t)NB * S_DIM * D_DIM * 2;   //  8.4 MB
  bf16* Vt  = (bf16*)ws;  ws += (size_t)NB * S_DIM * D_DIM * 2;   //  8.4 MB
  bf16* Mbf = (bf16*)ws;  ws += (size_t)NB * S_DIM * D_DIM * 2;   //  8.4 MB
  bf16* Wbf = (bf16*)ws;  ws += (size_t)NB * S_DIM * S_DIM * 2;   // 33.5 MB
  float* v2 = (float*)ws; ws += (size_t)NB * S_DIM * 4;
  float* m2 = (float*)ws; ws += (size_t)NB * S_DIM * 4;
  float* l1 = (float*)ws; ws += (size_t)NB * S_DIM * 4;

  int nA4 = NB * S_DIM * S_DIM / 4;
  int nV4 = NB * S_DIM * D_DIM / 4;
  cast_kernel<<<nA4 / 256, 256, 0, stream>>>(A, Abf, nA4);
  cast_kernel<<<nV4 / 256, 256, 0, stream>>>(V, Vbf, nV4);
  transpose_cast_kernel<<<dim3(D_DIM / 64, S_DIM / 64, NB), 256, 0, stream>>>(V, Vt);
  rownorm_kernel<<<NB * S_DIM / 4, 256, 0, stream>>>(Vbf, v2);

  // M0 = A @ V   (NT vs Vt)
  gemm_kernel<0><<<dim3(D_DIM / 128, S_DIM / 128, NB), 256, 0, stream>>>(
      Abf, Vt, S_DIM, D_DIM, S_DIM, Mbf, nullptr, nullptr, nullptr, nullptr, nullptr, nullptr);

  for (int it = 0; it < 3; ++it) {
    rownorm_kernel<<<NB * S_DIM / 4, 256, 0, stream>>>(Mbf, m2);
    hipMemsetAsync(l1, 0, (size_t)NB * S_DIM * 4, stream);
    // P = M @ V^T fused with dist/weight epilogue -> Wbf, l1
    gemm_kernel<1><<<dim3(S_DIM / 128, S_DIM / 128, NB), 256, 0, stream>>>(
        Mbf, Vbf, S_DIM, S_DIM, D_DIM, nullptr, nullptr, m2, v2, Abf, Wbf, l1);
    // M = (W @ V) / l1
    if (it < 2) {
      gemm_kernel<2><<<dim3(D_DIM / 128, S_DIM / 128, NB), 256, 0, stream>>>(
          Wbf, Vt, S_DIM, D_DIM, S_DIM, Mbf, nullptr, nullptr, nullptr, nullptr, nullptr, l1);
    } else {
      gemm_kernel<3><<<dim3(D_DIM / 128, S_DIM / 128, NB), 256, 0, stream>>>(
          Wbf, Vt, S_DIM, D_DIM, S_DIM, nullptr, out, nullptr, nullptr, nullptr, nullptr, l1);
    }
  }
}

// Round 2
// 436.680 us; speedup vs baseline: 1.1111x; 1.1111x over previous
//
#include <hip/hip_runtime.h>

// RobustSum: M = A@V; 3x { dist=cdist(M,V); w=1/(dist+eps); ww=w*A;
//                          M = (ww/rowsum(ww)) @ V }   (T=1.0)
// bf16 MFMA everywhere; tolerance is 2% of ref absmax (round-1 margin: 5x).
//
// Round 2: (a) MODE1 epilogue vectorized via LDS transpose of w (was 128
// scalar 2B loads+stores per thread -> 4x bf16x8 vector ops); (b) N=512
// GEMMs split-K=2 (256 -> 512 blocks, 2/CU) + reducer that fuses 1/l1
// scaling, bf16 cast, and m2 (rownorm) computation.

typedef __bf16 bf16;
typedef bf16 bf16x4 __attribute__((ext_vector_type(4)));
typedef bf16 bf16x8 __attribute__((ext_vector_type(8)));
typedef float f32x4 __attribute__((ext_vector_type(4)));

#define S_DIM 2048
#define D_DIM 512
#define NB    4
#define EPSILON 0.01f

// ---------------- cast fp32 -> bf16 (vectorized x4) ----------------
__global__ void cast_kernel(const float* __restrict__ in, bf16* __restrict__ out, int n4) {
  int i = blockIdx.x * blockDim.x + threadIdx.x;
  if (i >= n4) return;
  float4 v = ((const float4*)in)[i];
  bf16x4 o = { (bf16)v.x, (bf16)v.y, (bf16)v.z, (bf16)v.w };
  ((bf16x4*)out)[i] = o;
}

// ---------------- transpose + cast: V (S x D) -> Vt (D x S) ----------------
__global__ void transpose_cast_kernel(const float* __restrict__ V, bf16* __restrict__ Vt) {
  __shared__ float tile[64][68];
  int b  = blockIdx.z;
  int c0 = blockIdx.x * 64;
  int r0 = blockIdx.y * 64;
  const float* Vb = V  + (size_t)b * S_DIM * D_DIM;
  bf16*       Vtb = Vt + (size_t)b * S_DIM * D_DIM;
  int tx = threadIdx.x & 15, ty = threadIdx.x >> 4;
#pragma unroll
  for (int i = 0; i < 4; ++i) {
    int r = ty + i * 16;
    float4 v = *(const float4*)(Vb + (size_t)(r0 + r) * D_DIM + (c0 + tx * 4));
    tile[r][tx * 4 + 0] = v.x; tile[r][tx * 4 + 1] = v.y;
    tile[r][tx * 4 + 2] = v.z; tile[r][tx * 4 + 3] = v.w;
  }
  __syncthreads();
#pragma unroll
  for (int i = 0; i < 4; ++i) {
    int c = ty + i * 16;
    bf16x4 o = { (bf16)tile[tx * 4 + 0][c], (bf16)tile[tx * 4 + 1][c],
                 (bf16)tile[tx * 4 + 2][c], (bf16)tile[tx * 4 + 3][c] };
    *(bf16x4*)(Vtb + (size_t)(c0 + c) * S_DIM + (r0 + tx * 4)) = o;
  }
}

// ---------------- row L2^2 of (rows x 512) bf16, one wave/row (v2 only) ----------------
__global__ void rownorm_kernel(const bf16* __restrict__ X, float* __restrict__ out) {
  int row  = blockIdx.x * 4 + (threadIdx.x >> 6);
  int lane = threadIdx.x & 63;
  bf16x8 v = *(const bf16x8*)(X + (size_t)row * D_DIM + lane * 8);
  float s = 0.f;
#pragma unroll
  for (int i = 0; i < 8; ++i) { float f = (float)v[i]; s += f * f; }
#pragma unroll
  for (int off = 32; off > 0; off >>= 1) s += __shfl_down(s, off);
  if (lane == 0) out[row] = s;
}

// ---------------- NT GEMM: C[M,N] = Amat(MxK) * Bmat(NxK)^T ----------------
// MODE 1: P-GEMM (K=512, grid z=NB): dist/weight epilogue -> Wbf (vectorized
//         via LDS transpose) + l1 row sums (atomic).
// MODE 4: split-K=2 (grid z=2*NB): fp32 partial C to part[ks][bz].
template <int MODE>
__global__ __launch_bounds__(256)
void gemm_kernel(const bf16* __restrict__ Amat, const bf16* __restrict__ Bmat,
                 int M, int N, int K,
                 float* __restrict__ Cf,
                 const float* __restrict__ m2, const float* __restrict__ v2,
                 const bf16* __restrict__ Aw, bf16* __restrict__ Wout,
                 float* __restrict__ l1) {
  int bz, ks, kbeg, kend;
  if (MODE == 4) { bz = blockIdx.z >> 1; ks = blockIdx.z & 1; kbeg = ks * (K >> 1); kend = kbeg + (K >> 1); }
  else           { bz = blockIdx.z;      ks = 0;              kbeg = 0;             kend = K; }
  const int row0 = blockIdx.y * 128;
  const int col0 = blockIdx.x * 128;
  const bf16* Ab = Amat + (size_t)bz * M * K;
  const bf16* Bb = Bmat + (size_t)bz * N * K;

  // union: staging (2 x 8192 B) and MODE1 epilogue w-buffer (32 x 132 fp32)
  __shared__ char smem[16896];
  bf16*  ldsA = (bf16*)smem;
  bf16*  ldsB = (bf16*)(smem + 8192);
  float* ldsW = (float*)smem;

  const int tid  = threadIdx.x;
  const int wave = tid >> 6;
  const int lane = tid & 63;
  const int wr   = wave >> 1;
  const int wc   = wave & 1;
  const int q    = lane >> 4;
  const int c16  = lane & 15;

  f32x4 acc[4][4] = {};

  for (int k0 = kbeg; k0 < kend; k0 += 32) {
#pragma unroll
    for (int i = 0; i < 2; ++i) {
      int eoff = (wave * 2 + i) * 512 + lane * 8;
      int r = eoff >> 5;
      int c = eoff & 31;
      __builtin_amdgcn_global_load_lds(
          (const __attribute__((address_space(1))) void*)(Ab + (size_t)(row0 + r) * K + (k0 + c)),
          (__attribute__((address_space(3))) void*)(ldsA + (wave * 2 + i) * 512), 16, 0, 0);
      __builtin_amdgcn_global_load_lds(
          (const __attribute__((address_space(1))) void*)(Bb + (size_t)(col0 + r) * K + (k0 + c)),
          (__attribute__((address_space(3))) void*)(ldsB + (wave * 2 + i) * 512), 16, 0, 0);
    }
    __syncthreads();

    bf16x8 afr[4], bfr[4];
#pragma unroll
    for (int mt = 0; mt < 4; ++mt)
      afr[mt] = *(const bf16x8*)(ldsA + (size_t)(wr * 64 + mt * 16 + c16) * 32 + q * 8);
#pragma unroll
    for (int nt = 0; nt < 4; ++nt)
      bfr[nt] = *(const bf16x8*)(ldsB + (size_t)(wc * 64 + nt * 16 + c16) * 32 + q * 8);
#pragma unroll
    for (int mt = 0; mt < 4; ++mt)
#pragma unroll
      for (int nt = 0; nt < 4; ++nt)
        acc[mt][nt] = __builtin_amdgcn_mfma_f32_16x16x32_bf16(afr[mt], bfr[nt], acc[mt][nt], 0, 0, 0);
    __syncthreads();
  }

  // C/D layout: col = lane&15, row = (lane>>4)*4 + reg (m89-verified)
  const int rowBase = row0 + wr * 64 + q * 4;
  const int colBase = col0 + wc * 64 + c16;

  if (MODE == 4) {
    float* Cp = Cf + ((size_t)ks * NB + bz) * ((size_t)M * N);
#pragma unroll
    for (int mt = 0; mt < 4; ++mt)
#pragma unroll
      for (int r = 0; r < 4; ++r) {
        int gi = rowBase + mt * 16 + r;
#pragma unroll
        for (int nt = 0; nt < 4; ++nt)
          Cp[(size_t)gi * N + (colBase + nt * 16)] = acc[mt][nt][r];
      }
  } else {
    // ---- phase 1 (registers): w = 1/(sqrt(max(m2+v2-2P,0)) + eps), in place
    const float* m2b = m2 + (size_t)bz * M;
    const float* v2b = v2 + (size_t)bz * N;
    float v2v[4];
#pragma unroll
    for (int nt = 0; nt < 4; ++nt) v2v[nt] = v2b[colBase + nt * 16];
#pragma unroll
    for (int mt = 0; mt < 4; ++mt)
#pragma unroll
      for (int r = 0; r < 4; ++r) {
        float m2v = m2b[rowBase + mt * 16 + r];
#pragma unroll
        for (int nt = 0; nt < 4; ++nt) {
          float p  = acc[mt][nt][r];
          float d2 = fmaxf(m2v + v2v[nt] - 2.f * p, 0.f);
          acc[mt][nt][r] = 1.f / (sqrtf(d2) + EPSILON);
        }
      }

    // ---- phase 2: LDS transpose (4 quarters of 32 rows), vectorized A/W I/O
    const bf16* Awb = Aw + (size_t)bz * M * N;
    bf16*       Wob = Wout + (size_t)bz * M * N;
    float*      l1b = l1 + (size_t)bz * M;
    const int lr = tid >> 3;   // 0..31  read row within quarter
    const int sub = tid & 7;   // 0..7   16-col chunk
#pragma unroll
    for (int k = 0; k < 4; ++k) {
      __syncthreads();  // protect LDS reuse (staging / previous quarter)
      if (wr == (k >> 1)) {
#pragma unroll
        for (int m = 0; m < 2; ++m) {
          int mt = 2 * (k & 1) + m;
#pragma unroll
          for (int nt = 0; nt < 4; ++nt)
#pragma unroll
            for (int r = 0; r < 4; ++r)
              ldsW[(m * 16 + q * 4 + r) * 132 + wc * 64 + nt * 16 + c16] = acc[mt][nt][r];
        }
      }
      __syncthreads();
      int gi = row0 + 32 * k + lr;
      const float* wp = ldsW + lr * 132 + sub * 16;
      float4 w0 = *(const float4*)(wp + 0);
      float4 w1 = *(const float4*)(wp + 4);
      float4 w2 = *(const float4*)(wp + 8);
      float4 w3 = *(const float4*)(wp + 12);
      float wv_[16] = { w0.x, w0.y, w0.z, w0.w, w1.x, w1.y, w1.z, w1.w,
                        w2.x, w2.y, w2.z, w2.w, w3.x, w3.y, w3.z, w3.w };
      const bf16* ap = Awb + (size_t)gi * N + (col0 + sub * 16);
      bf16x8 a0 = *(const bf16x8*)(ap);
      bf16x8 a1 = *(const bf16x8*)(ap + 8);
      bf16x8 o0, o1;
      float rs = 0.f;
#pragma unroll
      for (int e = 0; e < 8; ++e) {
        float x0 = wv_[e] * (float)a0[e];
        float x1 = wv_[e + 8] * (float)a1[e];
        o0[e] = (bf16)x0; o1[e] = (bf16)x1;
        rs += fabsf(x0) + fabsf(x1);
      }
      bf16* op = Wob + (size_t)gi * N + (col0 + sub * 16);
      *(bf16x8*)(op)     = o0;
      *(bf16x8*)(op + 8) = o1;
      rs += __shfl_xor(rs, 1);
      rs += __shfl_xor(rs, 2);
      rs += __shfl_xor(rs, 4);
      if (sub == 0) atomicAdd(&l1b[gi], rs);
    }
  }
}

// ---------------- reduce split-K partials ----------------
// RMODE 0: Mbf + m2 ;  1: scale 1/l1 -> Mbf + m2 ;  2: scale 1/l1 -> fp32 out
template <int RMODE>
__global__ void reduce_kernel(const float* __restrict__ part, const float* __restrict__ l1,
                              bf16* __restrict__ Mo, float* __restrict__ Fo,
                              float* __restrict__ m2) {
  int wave = threadIdx.x >> 6, lane = threadIdx.x & 63;
  int rg = blockIdx.x * 4 + wave;          // 0..NB*S-1
  const float* p0 = part + (size_t)rg * D_DIM + lane * 8;
  const float* p1 = p0 + (size_t)NB * S_DIM * D_DIM;
  float4 a0 = *(const float4*)(p0);
  float4 a1 = *(const float4*)(p0 + 4);
  float4 b0 = *(const float4*)(p1);
  float4 b1 = *(const float4*)(p1 + 4);
  float v[8] = { a0.x + b0.x, a0.y + b0.y, a0.z + b0.z, a0.w + b0.w,
                 a1.x + b1.x, a1.y + b1.y, a1.z + b1.z, a1.w + b1.w };
  float sc = 1.f;
  if (RMODE >= 1) sc = 1.f / fmaxf(l1[rg], 1e-12f);
  float s = 0.f;
#pragma unroll
  for (int e = 0; e < 8; ++e) { v[e] *= sc; s += v[e] * v[e]; }
  if (RMODE == 2) {
    float4 o0 = { v[0], v[1], v[2], v[3] }, o1 = { v[4], v[5], v[6], v[7] };
    float* op = Fo + (size_t)rg * D_DIM + lane * 8;
    *(float4*)(op) = o0; *(float4*)(op + 4) = o1;
  } else {
    bf16x8 o;
#pragma unroll
    for (int e = 0; e < 8; ++e) o[e] = (bf16)v[e];
    *(bf16x8*)(Mo + (size_t)rg * D_DIM + lane * 8) = o;
#pragma unroll
    for (int off = 32; off > 0; off >>= 1) s += __shfl_xor(s, off);
    if (lane == 0) m2[rg] = s;
  }
}

extern "C" void kernel_launch(void* const* d_in, const int* in_sizes, int n_in,
                              void* d_out, int out_size, void* d_ws, size_t ws_size,
                              hipStream_t stream) {
  const float* A = (const float*)d_in[0];  // (4, 2048, 2048)
  const float* V = (const float*)d_in[1];  // (4, 2048, 512)
  float* out = (float*)d_out;              // (4, 2048, 512) fp32

  char* ws = (char*)d_ws;
  bf16* Abf = (bf16*)ws;   ws += (size_t)NB * S_DIM * S_DIM * 2;       // 33.5 MB
  bf16* Vbf = (bf16*)ws;   ws += (size_t)NB * S_DIM * D_DIM * 2;       //  8.4 MB
  bf16* Vt  = (bf16*)ws;   ws += (size_t)NB * S_DIM * D_DIM * 2;       //  8.4 MB
  bf16* Mbf = (bf16*)ws;   ws += (size_t)NB * S_DIM * D_DIM * 2;       //  8.4 MB
  bf16* Wbf = (bf16*)ws;   ws += (size_t)NB * S_DIM * S_DIM * 2;       // 33.5 MB
  float* part = (float*)ws; ws += (size_t)2 * NB * S_DIM * D_DIM * 4;  // 33.5 MB
  float* v2 = (float*)ws;  ws += (size_t)NB * S_DIM * 4;
  float* m2 = (float*)ws;  ws += (size_t)NB * S_DIM * 4;
  float* l1 = (float*)ws;  ws += (size_t)NB * S_DIM * 4;

  int nA4 = NB * S_DIM * S_DIM / 4;
  int nV4 = NB * S_DIM * D_DIM / 4;
  cast_kernel<<<nA4 / 256, 256, 0, stream>>>(A, Abf, nA4);
  cast_kernel<<<nV4 / 256, 256, 0, stream>>>(V, Vbf, nV4);
  transpose_cast_kernel<<<dim3(D_DIM / 64, S_DIM / 64, NB), 256, 0, stream>>>(V, Vt);
  rownorm_kernel<<<NB * S_DIM / 4, 256, 0, stream>>>(Vbf, v2);

  // M0 = A @ V  (split-K=2 -> partials -> reduce with m2)
  gemm_kernel<4><<<dim3(D_DIM / 128, S_DIM / 128, NB * 2), 256, 0, stream>>>(
      Abf, Vt, S_DIM, D_DIM, S_DIM, part, nullptr, nullptr, nullptr, nullptr, nullptr);
  reduce_kernel<0><<<NB * S_DIM / 4, 256, 0, stream>>>(part, nullptr, Mbf, nullptr, m2);

  for (int it = 0; it < 3; ++it) {
    hipMemsetAsync(l1, 0, (size_t)NB * S_DIM * 4, stream);
    // P = M @ V^T fused with dist/weight epilogue -> Wbf, l1
    gemm_kernel<1><<<dim3(S_DIM / 128, S_DIM / 128, NB), 256, 0, stream>>>(
        Mbf, Vbf, S_DIM, S_DIM, D_DIM, nullptr, m2, v2, Abf, Wbf, l1);
    // M = (W @ V) / l1  (split-K=2 -> partials -> reduce)
    gemm_kernel<4><<<dim3(D_DIM / 128, S_DIM / 128, NB * 2), 256, 0, stream>>>(
        Wbf, Vt, S_DIM, D_DIM, S_DIM, part, nullptr, nullptr, nullptr, nullptr, nullptr);
    if (it < 2)
      reduce_kernel<1><<<NB * S_DIM / 4, 256, 0, stream>>>(part, l1, Mbf, nullptr, m2);
    else
      reduce_kernel<2><<<NB * S_DIM / 4, 256, 0, stream>>>(part, l1, nullptr, out, nullptr);
  }
}

// Round 3
// 354.481 us; speedup vs baseline: 1.3687x; 1.2319x over previous
//
#include <hip/hip_runtime.h>

// RobustSum: M = A@V; 3x { dist=cdist(M,V); w=1/(dist+eps); ww=w*A;
//                          M = (ww/rowsum(ww)) @ V }   (T=1.0)
// bf16 MFMA; tolerance = 2% of ref absmax (round-2 margin: 5.3x).
//
// Round 3: (a) BK=64 K-loop (half the vmcnt(0) barrier drains, 2x MFMA per
// barrier) with XOR-swizzled LDS layout (BK=64 row stride = 32 banks ->
// unswizzled b128 frag reads would be 16-way conflicted); (b) fast
// v_sqrt/v_rcp approximations in the dist/weight epilogue (precise div/sqrt
// was ~10us of VALU); (c) split-K partials in bf16 + vectorized partial
// stores via the LDS-transpose quarters (was 64 scalar dword stores/thread).

typedef __bf16 bf16;
typedef bf16 bf16x4 __attribute__((ext_vector_type(4)));
typedef bf16 bf16x8 __attribute__((ext_vector_type(8)));
typedef float f32x4 __attribute__((ext_vector_type(4)));

#define S_DIM 2048
#define D_DIM 512
#define NB    4
#define EPSILON 0.01f

// ---------------- cast fp32 -> bf16 (vectorized x4) ----------------
__global__ void cast_kernel(const float* __restrict__ in, bf16* __restrict__ out, int n4) {
  int i = blockIdx.x * blockDim.x + threadIdx.x;
  if (i >= n4) return;
  float4 v = ((const float4*)in)[i];
  bf16x4 o = { (bf16)v.x, (bf16)v.y, (bf16)v.z, (bf16)v.w };
  ((bf16x4*)out)[i] = o;
}

// ---------------- transpose + cast: V (S x D) -> Vt (D x S) ----------------
__global__ void transpose_cast_kernel(const float* __restrict__ V, bf16* __restrict__ Vt) {
  __shared__ float tile[64][68];
  int b  = blockIdx.z;
  int c0 = blockIdx.x * 64;
  int r0 = blockIdx.y * 64;
  const float* Vb = V  + (size_t)b * S_DIM * D_DIM;
  bf16*       Vtb = Vt + (size_t)b * S_DIM * D_DIM;
  int tx = threadIdx.x & 15, ty = threadIdx.x >> 4;
#pragma unroll
  for (int i = 0; i < 4; ++i) {
    int r = ty + i * 16;
    float4 v = *(const float4*)(Vb + (size_t)(r0 + r) * D_DIM + (c0 + tx * 4));
    tile[r][tx * 4 + 0] = v.x; tile[r][tx * 4 + 1] = v.y;
    tile[r][tx * 4 + 2] = v.z; tile[r][tx * 4 + 3] = v.w;
  }
  __syncthreads();
#pragma unroll
  for (int i = 0; i < 4; ++i) {
    int c = ty + i * 16;
    bf16x4 o = { (bf16)tile[tx * 4 + 0][c], (bf16)tile[tx * 4 + 1][c],
                 (bf16)tile[tx * 4 + 2][c], (bf16)tile[tx * 4 + 3][c] };
    *(bf16x4*)(Vtb + (size_t)(c0 + c) * S_DIM + (r0 + tx * 4)) = o;
  }
}

// ---------------- row L2^2 of (rows x 512) bf16, one wave/row (v2 only) ----------------
__global__ void rownorm_kernel(const bf16* __restrict__ X, float* __restrict__ out) {
  int row  = blockIdx.x * 4 + (threadIdx.x >> 6);
  int lane = threadIdx.x & 63;
  bf16x8 v = *(const bf16x8*)(X + (size_t)row * D_DIM + lane * 8);
  float s = 0.f;
#pragma unroll
  for (int i = 0; i < 8; ++i) { float f = (float)v[i]; s += f * f; }
#pragma unroll
  for (int off = 32; off > 0; off >>= 1) s += __shfl_down(s, off);
  if (lane == 0) out[row] = s;
}

// ---------------- NT GEMM: C[M,N] = Amat(MxK) * Bmat(NxK)^T, BK=64 ----------------
// MODE 1: P-GEMM (grid z=NB): dist/weight epilogue -> Wbf + l1 (atomic).
// MODE 4: split-K=2 (grid z=2*NB): bf16 partial C, vectorized via LDS quarters.
// LDS layout swizzle: 16B chunk p within a 128B row holds logical chunk
// p ^ (row&7); staging picks the global column accordingly (the
// global_load_lds LDS dest is fixed at base + lane*16).
template <int MODE>
__global__ __launch_bounds__(256, 4)
void gemm_kernel(const bf16* __restrict__ Amat, const bf16* __restrict__ Bmat,
                 int M, int N, int K,
                 bf16* __restrict__ Cp,
                 const float* __restrict__ m2, const float* __restrict__ v2,
                 const bf16* __restrict__ Aw, bf16* __restrict__ Wout,
                 float* __restrict__ l1) {
  int bz, ks, kbeg, kend;
  if (MODE == 4) { bz = blockIdx.z >> 1; ks = blockIdx.z & 1; kbeg = ks * (K >> 1); kend = kbeg + (K >> 1); }
  else           { bz = blockIdx.z;      ks = 0;              kbeg = 0;             kend = K; }
  const int row0 = blockIdx.y * 128;
  const int col0 = blockIdx.x * 128;
  const bf16* Ab = Amat + (size_t)bz * M * K;
  const bf16* Bb = Bmat + (size_t)bz * N * K;

  // union: staging (2 x 16384 B, 128x64 bf16 each) and epilogue 32x132 fp32
  __shared__ char smem[32768];
  bf16*  ldsA = (bf16*)smem;
  bf16*  ldsB = (bf16*)(smem + 16384);
  float* ldsW = (float*)smem;

  const int tid  = threadIdx.x;
  const int wave = tid >> 6;
  const int lane = tid & 63;
  const int wr   = wave >> 1;
  const int wc   = wave & 1;
  const int q    = lane >> 4;
  const int c16  = lane & 15;

  // staging source coords (swizzled)
  const int srow = lane >> 3;                       // row within 8-row issue slab
  const int scol = ((lane & 7) ^ srow) * 8;         // swizzled source column (elems)

  f32x4 acc[4][4] = {};

  for (int k0 = kbeg; k0 < kend; k0 += 64) {
#pragma unroll
    for (int i = 0; i < 4; ++i) {
      int slot = wave * 4 + i;                      // 0..15, 8 rows each
      int r = slot * 8 + srow;
      __builtin_amdgcn_global_load_lds(
          (const __attribute__((address_space(1))) void*)(Ab + (size_t)(row0 + r) * K + (k0 + scol)),
          (__attribute__((address_space(3))) void*)(ldsA + slot * 512), 16, 0, 0);
      __builtin_amdgcn_global_load_lds(
          (const __attribute__((address_space(1))) void*)(Bb + (size_t)(col0 + r) * K + (k0 + scol)),
          (__attribute__((address_space(3))) void*)(ldsB + slot * 512), 16, 0, 0);
    }
    __syncthreads();

#pragma unroll
    for (int kk = 0; kk < 2; ++kk) {
      bf16x8 afr[4], bfr[4];
#pragma unroll
      for (int mt = 0; mt < 4; ++mt) {
        int R = wr * 64 + mt * 16 + c16;
        int p = ((kk << 2) + q) ^ (c16 & 7);
        afr[mt] = *(const bf16x8*)(ldsA + (size_t)R * 64 + p * 8);
      }
#pragma unroll
      for (int nt = 0; nt < 4; ++nt) {
        int R = wc * 64 + nt * 16 + c16;
        int p = ((kk << 2) + q) ^ (c16 & 7);
        bfr[nt] = *(const bf16x8*)(ldsB + (size_t)R * 64 + p * 8);
      }
#pragma unroll
      for (int mt = 0; mt < 4; ++mt)
#pragma unroll
        for (int nt = 0; nt < 4; ++nt)
          acc[mt][nt] = __builtin_amdgcn_mfma_f32_16x16x32_bf16(afr[mt], bfr[nt], acc[mt][nt], 0, 0, 0);
    }
    __syncthreads();
  }

  // C/D layout: col = lane&15, row = (lane>>4)*4 + reg (m89-verified)
  const int rowBase = row0 + wr * 64 + q * 4;
  const int colBase = col0 + wc * 64 + c16;

  if (MODE == 1) {
    // phase 1 (registers): w = rcp(sqrt(max(m2+v2-2P,0)) + eps), in place.
    // v_sqrt_f32/v_rcp_f32 approx (~2^-22 rel) -- far inside the 2% budget.
    const float* m2b = m2 + (size_t)bz * M;
    const float* v2b = v2 + (size_t)bz * N;
    float v2v[4];
#pragma unroll
    for (int nt = 0; nt < 4; ++nt) v2v[nt] = v2b[colBase + nt * 16];
#pragma unroll
    for (int mt = 0; mt < 4; ++mt)
#pragma unroll
      for (int r = 0; r < 4; ++r) {
        float m2v = m2b[rowBase + mt * 16 + r];
#pragma unroll
        for (int nt = 0; nt < 4; ++nt) {
          float d2 = fmaxf(m2v + v2v[nt] - 2.f * acc[mt][nt][r], 0.f);
          acc[mt][nt][r] = __builtin_amdgcn_rcpf(__builtin_amdgcn_sqrtf(d2) + EPSILON);
        }
      }
  }

  // phase 2: LDS transpose in 4 quarters of 32 rows -> vectorized global I/O
  const int lr  = tid >> 3;   // 0..31 row within quarter
  const int sub = tid & 7;    // 0..7  16-col chunk
#pragma unroll
  for (int k = 0; k < 4; ++k) {
    __syncthreads();  // protect LDS reuse (staging buffers / previous quarter)
    if (wr == (k >> 1)) {
#pragma unroll
      for (int m = 0; m < 2; ++m) {
        int mt = 2 * (k & 1) + m;
#pragma unroll
        for (int nt = 0; nt < 4; ++nt)
#pragma unroll
          for (int r = 0; r < 4; ++r)
            ldsW[(m * 16 + q * 4 + r) * 132 + wc * 64 + nt * 16 + c16] = acc[mt][nt][r];
      }
    }
    __syncthreads();
    int gi = row0 + 32 * k + lr;
    const float* wp = ldsW + lr * 132 + sub * 16;
    float4 w0 = *(const float4*)(wp + 0);
    float4 w1 = *(const float4*)(wp + 4);
    float4 w2 = *(const float4*)(wp + 8);
    float4 w3 = *(const float4*)(wp + 12);
    float wv_[16] = { w0.x, w0.y, w0.z, w0.w, w1.x, w1.y, w1.z, w1.w,
                      w2.x, w2.y, w2.z, w2.w, w3.x, w3.y, w3.z, w3.w };
    if (MODE == 1) {
      const bf16* Awb = Aw + (size_t)bz * M * N;
      bf16*       Wob = Wout + (size_t)bz * M * N;
      float*      l1b = l1 + (size_t)bz * M;
      const bf16* ap = Awb + (size_t)gi * N + (col0 + sub * 16);
      bf16x8 a0 = *(const bf16x8*)(ap);
      bf16x8 a1 = *(const bf16x8*)(ap + 8);
      bf16x8 o0, o1;
      float rs = 0.f;
#pragma unroll
      for (int e = 0; e < 8; ++e) {
        float x0 = wv_[e] * (float)a0[e];
        float x1 = wv_[e + 8] * (float)a1[e];
        o0[e] = (bf16)x0; o1[e] = (bf16)x1;
        rs += fabsf(x0) + fabsf(x1);
      }
      bf16* op = Wob + (size_t)gi * N + (col0 + sub * 16);
      *(bf16x8*)(op)     = o0;
      *(bf16x8*)(op + 8) = o1;
      rs += __shfl_xor(rs, 1);
      rs += __shfl_xor(rs, 2);
      rs += __shfl_xor(rs, 4);
      if (sub == 0) atomicAdd(&l1b[gi], rs);
    } else {
      bf16* Cb = Cp + ((size_t)ks * NB + bz) * ((size_t)M * N);
      bf16x8 o0, o1;
#pragma unroll
      for (int e = 0; e < 8; ++e) { o0[e] = (bf16)wv_[e]; o1[e] = (bf16)wv_[e + 8]; }
      bf16* op = Cb + (size_t)gi * N + (col0 + sub * 16);
      *(bf16x8*)(op)     = o0;
      *(bf16x8*)(op + 8) = o1;
    }
  }
}

// ---------------- reduce split-K bf16 partials ----------------
// RMODE 0: Mbf + m2 ;  1: scale 1/l1 -> Mbf + m2 ;  2: scale 1/l1 -> fp32 out
template <int RMODE>
__global__ void reduce_kernel(const bf16* __restrict__ part, const float* __restrict__ l1,
                              bf16* __restrict__ Mo, float* __restrict__ Fo,
                              float* __restrict__ m2) {
  int wave = threadIdx.x >> 6, lane = threadIdx.x & 63;
  int rg = blockIdx.x * 4 + wave;          // 0..NB*S-1
  const bf16* p0 = part + (size_t)rg * D_DIM + lane * 8;
  const bf16* p1 = p0 + (size_t)NB * S_DIM * D_DIM;
  bf16x8 a = *(const bf16x8*)p0;
  bf16x8 b = *(const bf16x8*)p1;
  float v[8];
#pragma unroll
  for (int e = 0; e < 8; ++e) v[e] = (float)a[e] + (float)b[e];
  float sc = 1.f;
  if (RMODE >= 1) sc = __builtin_amdgcn_rcpf(fmaxf(l1[rg], 1e-12f));
  float s = 0.f;
#pragma unroll
  for (int e = 0; e < 8; ++e) { v[e] *= sc; s += v[e] * v[e]; }
  if (RMODE == 2) {
    float4 o0 = { v[0], v[1], v[2], v[3] }, o1 = { v[4], v[5], v[6], v[7] };
    float* op = Fo + (size_t)rg * D_DIM + lane * 8;
    *(float4*)(op) = o0; *(float4*)(op + 4) = o1;
  } else {
    bf16x8 o;
#pragma unroll
    for (int e = 0; e < 8; ++e) o[e] = (bf16)v[e];
    *(bf16x8*)(Mo + (size_t)rg * D_DIM + lane * 8) = o;
#pragma unroll
    for (int off = 32; off > 0; off >>= 1) s += __shfl_xor(s, off);
    if (lane == 0) m2[rg] = s;
  }
}

extern "C" void kernel_launch(void* const* d_in, const int* in_sizes, int n_in,
                              void* d_out, int out_size, void* d_ws, size_t ws_size,
                              hipStream_t stream) {
  const float* A = (const float*)d_in[0];  // (4, 2048, 2048)
  const float* V = (const float*)d_in[1];  // (4, 2048, 512)
  float* out = (float*)d_out;              // (4, 2048, 512) fp32

  char* ws = (char*)d_ws;
  bf16* Abf = (bf16*)ws;   ws += (size_t)NB * S_DIM * S_DIM * 2;       // 33.5 MB
  bf16* Vbf = (bf16*)ws;   ws += (size_t)NB * S_DIM * D_DIM * 2;       //  8.4 MB
  bf16* Vt  = (bf16*)ws;   ws += (size_t)NB * S_DIM * D_DIM * 2;       //  8.4 MB
  bf16* Mbf = (bf16*)ws;   ws += (size_t)NB * S_DIM * D_DIM * 2;       //  8.4 MB
  bf16* Wbf = (bf16*)ws;   ws += (size_t)NB * S_DIM * S_DIM * 2;       // 33.5 MB
  bf16* part = (bf16*)ws;  ws += (size_t)2 * NB * S_DIM * D_DIM * 2;   // 16.8 MB
  float* v2 = (float*)ws;  ws += (size_t)NB * S_DIM * 4;
  float* m2 = (float*)ws;  ws += (size_t)NB * S_DIM * 4;
  float* l1 = (float*)ws;  ws += (size_t)NB * S_DIM * 4;

  int nA4 = NB * S_DIM * S_DIM / 4;
  int nV4 = NB * S_DIM * D_DIM / 4;
  cast_kernel<<<nA4 / 256, 256, 0, stream>>>(A, Abf, nA4);
  cast_kernel<<<nV4 / 256, 256, 0, stream>>>(V, Vbf, nV4);
  transpose_cast_kernel<<<dim3(D_DIM / 64, S_DIM / 64, NB), 256, 0, stream>>>(V, Vt);
  rownorm_kernel<<<NB * S_DIM / 4, 256, 0, stream>>>(Vbf, v2);

  // M0 = A @ V  (split-K=2 bf16 partials -> reduce with m2)
  gemm_kernel<4><<<dim3(D_DIM / 128, S_DIM / 128, NB * 2), 256, 0, stream>>>(
      Abf, Vt, S_DIM, D_DIM, S_DIM, part, nullptr, nullptr, nullptr, nullptr, nullptr);
  reduce_kernel<0><<<NB * S_DIM / 4, 256, 0, stream>>>(part, nullptr, Mbf, nullptr, m2);

  for (int it = 0; it < 3; ++it) {
    hipMemsetAsync(l1, 0, (size_t)NB * S_DIM * 4, stream);
    // P = M @ V^T fused with dist/weight epilogue -> Wbf, l1
    gemm_kernel<1><<<dim3(S_DIM / 128, S_DIM / 128, NB), 256, 0, stream>>>(
        Mbf, Vbf, S_DIM, S_DIM, D_DIM, nullptr, m2, v2, Abf, Wbf, l1);
    // M = (W @ V) / l1  (split-K=2 bf16 partials -> reduce)
    gemm_kernel<4><<<dim3(D_DIM / 128, S_DIM / 128, NB * 2), 256, 0, stream>>>(
        Wbf, Vt, S_DIM, D_DIM, S_DIM, part, nullptr, nullptr, nullptr, nullptr, nullptr);
    if (it < 2)
      reduce_kernel<1><<<NB * S_DIM / 4, 256, 0, stream>>>(part, l1, Mbf, nullptr, m2);
    else
      reduce_kernel<2><<<NB * S_DIM / 4, 256, 0, stream>>>(part, l1, nullptr, out, nullptr);
  }
}